// Round 3
// baseline (1201.833 us; speedup 1.0000x reference)
//
#include <hip/hip_runtime.h>

typedef __attribute__((ext_vector_type(8))) short bf16x8;
typedef __attribute__((ext_vector_type(16))) float f32x16;

#define SEQ 16
#define NAG 128
#define HD  512

__device__ __forceinline__ unsigned short f2bf(float x) {
  unsigned int u = __float_as_uint(x);
  return (unsigned short)((u + 0x7fffu + ((u >> 16) & 1u)) >> 16);  // RNE
}
__device__ __forceinline__ float sigm(float x) { return 1.0f / (1.0f + __expf(-x)); }
__device__ __forceinline__ float tanh_(float x) { return 2.0f / (1.0f + __expf(-2.0f * x)) - 1.0f; }

// Pack weights into MFMA-B-fragment order: Wpk[((tile*64 + ks)*64 + lane)*8 + e]
//   tile in [0,64): gate-col tile of 32;  ks in [0,64): k-step of 16
//   fragment: col = tile*32 + (lane&31), k = ks*16 + (lane>>5)*8 + e
//   k < 512 -> W_ih[:,k], else W_hh[:,k-512].  bsum[n] = b_ih[n]+b_hh[n].
__global__ void prep_pack(const float* __restrict__ Wih, const float* __restrict__ Whh,
                          const float* __restrict__ bih, const float* __restrict__ bhh,
                          unsigned short* __restrict__ Wpk, float* __restrict__ bsum) {
  const int t  = blockIdx.x >> 6;
  const int ks = blockIdx.x & 63;
  const int l  = threadIdx.x;
  const int n  = t * 32 + (l & 31);
  const int k  = ks * 16 + (l >> 5) * 8;
  const float* p = (k < 512) ? (Wih + (size_t)n * 512 + k) : (Whh + (size_t)n * 512 + (k - 512));
  float4 w0 = *reinterpret_cast<const float4*>(p);
  float4 w1 = *reinterpret_cast<const float4*>(p + 4);
  bf16x8 v = {(short)f2bf(w0.x), (short)f2bf(w0.y), (short)f2bf(w0.z), (short)f2bf(w0.w),
              (short)f2bf(w1.x), (short)f2bf(w1.y), (short)f2bf(w1.z), (short)f2bf(w1.w)};
  *reinterpret_cast<bf16x8*>(Wpk + ((size_t)blockIdx.x * 64 + l) * 8) = v;
  if (ks == 0 && l < 32) bsum[n] = bih[n] + bhh[n];
}

template <bool PACKED>
__device__ __forceinline__ bf16x8 loadBf(const float* __restrict__ Wih,
                                         const float* __restrict__ Whh,
                                         int tile, int ks, int lane) {
  int n = tile * 32 + (lane & 31);
  int k = ks * 16 + (lane >> 5) * 8;
  const float* p = (k < 512) ? (Wih + (size_t)n * 512 + k) : (Whh + (size_t)n * 512 + (k - 512));
  float4 w0 = *reinterpret_cast<const float4*>(p);
  float4 w1 = *reinterpret_cast<const float4*>(p + 4);
  return bf16x8{(short)f2bf(w0.x), (short)f2bf(w0.y), (short)f2bf(w0.z), (short)f2bf(w0.w),
                (short)f2bf(w1.x), (short)f2bf(w1.y), (short)f2bf(w1.z), (short)f2bf(w1.w)};
}

template <bool PACKED>
__global__ __launch_bounds__(1024, 4)
void lstm16w(const float* __restrict__ hxs, const float* __restrict__ cxs,
             const float* __restrict__ h_self, const float* __restrict__ h_inter,
             const int* __restrict__ reset,
             const unsigned short* __restrict__ Wpk, const float* __restrict__ bsum,
             const float* __restrict__ Wih, const float* __restrict__ Whh,
             const float* __restrict__ bih, const float* __restrict__ bhh,
             float* __restrict__ out) {
  __shared__ __align__(16) unsigned short x_lds[32 * 512];      // 32 KB
  __shared__ __align__(16) unsigned short h_lds[2][32 * 512];   // 64 KB

  const int tid  = threadIdx.x;
  const int w    = tid >> 6;       // 16 waves
  const int lane = tid & 63;
  const int colB = lane & 31;
  const int khB  = lane >> 5;
  const int row  = colB;           // A-row this lane reads

  const int bid    = blockIdx.x;
  const int traj   = bid >> 2;
  const int agent0 = (bid & 3) * 32;

  // staging mapping: 1024 threads -> 32 rows x 32 lanes
  const int rS  = tid >> 5;
  const int l32 = tid & 31;
  const int swS = (rS & 31) << 3;  // element-index XOR swizzle (32-row span)

  const size_t CYS = (size_t)SEQ * 64 * NAG * HD;  // 67108864

  { // stage h(0) = hxs[traj*SEQ] rows
    const float* src = hxs + ((size_t)traj * SEQ * NAG + (agent0 + rS)) * HD;
    #pragma unroll
    for (int p = 0; p < 4; ++p) {
      int k = p * 128 + l32 * 4;
      float4 v = *reinterpret_cast<const float4*>(src + k);
      ushort4 u4 = make_ushort4(f2bf(v.x), f2bf(v.y), f2bf(v.z), f2bf(v.w));
      *reinterpret_cast<ushort4*>(&h_lds[0][rS * 512 + (k ^ swS)]) = u4;
    }
  }

  // persistent per-lane state
  const int hd = w * 32 + colB;
  float c_reg[16];
  float biasv[4];
  {
    #pragma unroll
    for (int q = 0; q < 4; ++q)
      biasv[q] = PACKED ? bsum[q * 512 + hd] : (bih[q * 512 + hd] + bhh[q * 512 + hd]);
    const size_t cbase = ((size_t)traj * SEQ * NAG + agent0) * HD;
    #pragma unroll
    for (int reg = 0; reg < 16; ++reg) {
      int r = (reg & 3) + 8 * (reg >> 2) + 4 * khB;
      c_reg[reg] = cxs[cbase + (size_t)r * HD + hd];
    }
  }

  // wave-uniform packed-weight tile bases (tiles q*16 + w, q = gate quadrant)
  const unsigned short* Wt0 = Wpk + ((size_t)(0 * 16 + w)) * 64 * 64 * 8;
  const unsigned short* Wt1 = Wpk + ((size_t)(1 * 16 + w)) * 64 * 64 * 8;
  const unsigned short* Wt2 = Wpk + ((size_t)(2 * 16 + w)) * 64 * 64 * 8;
  const unsigned short* Wt3 = Wpk + ((size_t)(3 * 16 + w)) * 64 * 64 * 8;

  for (int t = 0; t < SEQ; ++t) {
    const int b  = traj * SEQ + t;
    const int mt = 1 - reset[b];
    const unsigned short* hcur = h_lds[t & 1];
    unsigned short*       hnxt = h_lds[(t & 1) ^ 1];

    { // stage x(t) = [h_self[b][:,256:] | h_inter[b]] -> bf16
      const float* srcs = h_self  + ((size_t)b * NAG + (agent0 + rS)) * HD + 256;
      const float* srci = h_inter + ((size_t)b * NAG + (agent0 + rS)) * 256;
      #pragma unroll
      for (int p = 0; p < 4; ++p) {
        int k = p * 128 + l32 * 4;
        const float* sp = (k < 256) ? (srcs + k) : (srci + (k - 256));
        float4 v = *reinterpret_cast<const float4*>(sp);
        ushort4 u4 = make_ushort4(f2bf(v.x), f2bf(v.y), f2bf(v.z), f2bf(v.w));
        *reinterpret_cast<ushort4*>(&x_lds[rS * 512 + (k ^ swS)]) = u4;
      }
      if (mt == 0) {  // h input of this step is exactly zero
        uint4* pz = (uint4*)h_lds[t & 1];
        pz[tid] = uint4{0, 0, 0, 0};
        pz[tid + 1024] = uint4{0, 0, 0, 0};
      }
    }
    __syncthreads();

    // bias pre-folded into accumulator init (col-only dependence)
    f32x16 acc[4];
    #pragma unroll
    for (int q = 0; q < 4; ++q)
      #pragma unroll
      for (int e = 0; e < 16; ++e) acc[q][e] = biasv[q];

    bf16x8 B0[4], B1[4];
    auto ldB = [&](bf16x8* B, int ks) {
      if (PACKED) {
        const int off = (ks * 64 + lane) * 8;
        B[0] = *reinterpret_cast<const bf16x8*>(Wt0 + off);
        B[1] = *reinterpret_cast<const bf16x8*>(Wt1 + off);
        B[2] = *reinterpret_cast<const bf16x8*>(Wt2 + off);
        B[3] = *reinterpret_cast<const bf16x8*>(Wt3 + off);
      } else {
        B[0] = loadBf<PACKED>(Wih, Whh, 0 * 16 + w, ks, lane);
        B[1] = loadBf<PACKED>(Wih, Whh, 1 * 16 + w, ks, lane);
        B[2] = loadBf<PACKED>(Wih, Whh, 2 * 16 + w, ks, lane);
        B[3] = loadBf<PACKED>(Wih, Whh, 3 * 16 + w, ks, lane);
      }
    };
    ldB(B0, 0);
    ldB(B1, 1);

    auto body = [&](int kp, const unsigned short* abuf) {
      const int ks0 = kp * 2;
      {
        const int ea = (((ks0 & 31) * 16 + khB * 8) ^ (row << 3));
        bf16x8 a = *reinterpret_cast<const bf16x8*>(abuf + row * 512 + ea);
        __builtin_amdgcn_s_setprio(1);
        acc[0] = __builtin_amdgcn_mfma_f32_32x32x16_bf16(a, B0[0], acc[0], 0, 0, 0);
        acc[1] = __builtin_amdgcn_mfma_f32_32x32x16_bf16(a, B0[1], acc[1], 0, 0, 0);
        acc[2] = __builtin_amdgcn_mfma_f32_32x32x16_bf16(a, B0[2], acc[2], 0, 0, 0);
        acc[3] = __builtin_amdgcn_mfma_f32_32x32x16_bf16(a, B0[3], acc[3], 0, 0, 0);
        __builtin_amdgcn_s_setprio(0);
        const int kn = (ks0 + 2 < 64) ? ks0 + 2 : 63;
        ldB(B0, kn);
      }
      {
        const int ea = ((((ks0 + 1) & 31) * 16 + khB * 8) ^ (row << 3));
        bf16x8 a = *reinterpret_cast<const bf16x8*>(abuf + row * 512 + ea);
        __builtin_amdgcn_s_setprio(1);
        acc[0] = __builtin_amdgcn_mfma_f32_32x32x16_bf16(a, B1[0], acc[0], 0, 0, 0);
        acc[1] = __builtin_amdgcn_mfma_f32_32x32x16_bf16(a, B1[1], acc[1], 0, 0, 0);
        acc[2] = __builtin_amdgcn_mfma_f32_32x32x16_bf16(a, B1[2], acc[2], 0, 0, 0);
        acc[3] = __builtin_amdgcn_mfma_f32_32x32x16_bf16(a, B1[3], acc[3], 0, 0, 0);
        __builtin_amdgcn_s_setprio(0);
        const int kn = (ks0 + 3 < 64) ? ks0 + 3 : 63;
        ldB(B1, kn);
      }
    };

    #pragma unroll 1
    for (int kp = 0; kp < 16; ++kp) body(kp, x_lds);      // k in [0,512): x half
    #pragma unroll 1
    for (int kp = 16; kp < 32; ++kp) body(kp, hcur);      // k in [512,1024): h half

    // LSTM cell: lane-local i/f/g/o at same (row, hd); bias already in acc
    #pragma unroll
    for (int reg = 0; reg < 16; ++reg) {
      float gi = acc[0][reg];
      float gf = acc[1][reg];
      float gg = acc[2][reg];
      float go = acc[3][reg];
      float cp = mt ? c_reg[reg] : 0.0f;
      float cn = sigm(gf) * cp + sigm(gi) * tanh_(gg);
      float hn = sigm(go) * tanh_(cn);
      c_reg[reg] = cn;
      int r = (reg & 3) + 8 * (reg >> 2) + 4 * khB;
      size_t ob = ((size_t)b * NAG + agent0 + r) * HD + hd;
      out[ob] = hn;
      out[CYS + ob] = cn;
      hnxt[r * 512 + (hd ^ (r << 3))] = f2bf(hn);
    }
    __syncthreads();
  }
}

extern "C" void kernel_launch(void* const* d_in, const int* in_sizes, int n_in,
                              void* d_out, int out_size, void* d_ws, size_t ws_size,
                              hipStream_t stream) {
  (void)in_sizes; (void)n_in; (void)out_size;
  const float* hxs     = (const float*)d_in[1];
  const float* cxs     = (const float*)d_in[2];
  const float* h_self  = (const float*)d_in[3];
  const float* h_inter = (const float*)d_in[4];
  const int*   reset   = (const int*)d_in[5];
  const float* Wih     = (const float*)d_in[6];
  const float* Whh     = (const float*)d_in[7];
  const float* bih     = (const float*)d_in[8];
  const float* bhh     = (const float*)d_in[9];
  float* out = (float*)d_out;

  const size_t needW = (size_t)2048 * 1024 * sizeof(unsigned short);  // 4 MB
  const size_t need  = needW + 2048 * sizeof(float);

  if (d_ws != nullptr && ws_size >= need) {
    unsigned short* Wpk = (unsigned short*)d_ws;
    float* bsum = (float*)((char*)d_ws + needW);
    prep_pack<<<4096, 64, 0, stream>>>(Wih, Whh, bih, bhh, Wpk, bsum);
    lstm16w<true><<<256, 1024, 0, stream>>>(hxs, cxs, h_self, h_inter, reset,
                                            Wpk, bsum, Wih, Whh, bih, bhh, out);
  } else {
    lstm16w<false><<<256, 1024, 0, stream>>>(hxs, cxs, h_self, h_inter, reset,
                                             nullptr, nullptr, Wih, Whh, bih, bhh, out);
  }
}